// Round 3
// baseline (587.720 us; speedup 1.0000x reference)
//
#include <hip/hip_runtime.h>

#define PI_F 3.14159265358979323846f

__device__ __forceinline__ float2 cmulf(float2 a, float c, float s) {
    return make_float2(a.x * c - a.y * s, a.x * s + a.y * c);
}

// Radix-4 butterfly, +i (inverse) convention — identical structure to the
// harness-verified 2048-pt Stockham kernel below.
#define BFLY4(v0, v1, v2, v3, o0, o1, o2, o3)                                  \
    {                                                                          \
        float a0r = v0.x + v2.x, a0i = v0.y + v2.y;                            \
        float a1r = v0.x - v2.x, a1i = v0.y - v2.y;                            \
        float a2r = v1.x + v3.x, a2i = v1.y + v3.y;                            \
        float a3r = v1.x - v3.x, a3i = v1.y - v3.y;                            \
        o0 = make_float2(a0r + a2r, a0i + a2i);                                \
        o1 = make_float2(a1r - a3i, a1i + a3r);                                \
        o2 = make_float2(a0r - a2r, a0i - a2i);                                \
        o3 = make_float2(a1r + a3i, a1i - a3r);                                \
    }

// LDS float2-index swizzle (verified round 2; conflict-free, kept as-is).
#define SW(e) ((e) ^ ((((e) >> 4) & 3) * 5))

// ---------------------------------------------------------------------------
// K1: one workgroup (512 threads) = one row of length 4096.  (VERIFIED)
// Makhoul half-spectrum + 2048-pt complex IFFT (Stockham radix-4).
// ---------------------------------------------------------------------------
template<bool IDXST>
__global__ __launch_bounds__(512, 8)
void row_fft_kernel(const float* __restrict__ in, float* __restrict__ out,
                    const float2* __restrict__ expk)
{
    __shared__ float smem[8192];               // 32 KB
    float*  xs   = smem;                       // staged row [4096]
    float2* bufB = (float2*)smem;              // overlays xs
    float2* bufA = (float2*)(smem + 4096);

    const int t = threadIdx.x;                 // 0..511
    const size_t row = blockIdx.x;
    const float* src = in  + row * 4096;
    float*       dst = out + row * 4096;

    {
        const float4* s4 = (const float4*)src;
        float4* x4 = (float4*)xs;
        x4[t]       = s4[t];
        x4[t + 512] = s4[t + 512];
    }
    __syncthreads();

    float2 z[4];
    #pragma unroll
    for (int i = 0; i < 4; i++) {
        int k = t + 512 * i;                   // 0..2047
        float Xa, Xra, Xb, Xrb;
        if (IDXST) {
            Xa  = xs[(4096 - k) & 4095];
            Xra = xs[k];
            Xb  = xs[2048 - k];
            Xrb = xs[2048 + k];
            if (k == 0) { Xa = 0.0f; Xra = 0.0f; }
        } else {
            Xa  = xs[k];
            Xra = xs[(4096 - k) & 4095];
            Xb  = xs[2048 + k];
            Xrb = xs[2048 - k];
            if (k == 0) Xra = 0.0f;
        }
        float2 ea = expk[k];
        float2 eb = expk[k + 2048];
        float Var = 0.5f * (Xa * ea.x + Xra * ea.y);
        float Vai = 0.5f * (Xa * ea.y - Xra * ea.x);
        float Vbr = 0.5f * (Xb * eb.x + Xrb * eb.y);
        float Vbi = 0.5f * (Xb * eb.y - Xrb * eb.x);
        float Ar = Var + Vbr, Ai = Vai + Vbi;
        float Dr = Var - Vbr, Di = Vai - Vbi;
        float cw, sw;
        __sincosf(PI_F * (float)k * (1.0f / 2048.0f), &sw, &cw);
        float Br = Dr * cw - Di * sw;
        float Bi = Dr * sw + Di * cw;
        z[i] = make_float2(Ar - Bi, Ai + Br);
    }

    {
        float2 v0 = z[0], v1 = z[1], v2 = z[2], v3 = z[3];
        int e = t << 2;
        BFLY4(v0, v1, v2, v3,
              bufA[SW(e)], bufA[SW(e + 1)], bufA[SW(e + 2)], bufA[SW(e + 3)]);
    }
    __syncthreads();

    float2* sb = bufA;
    float2* db = bufB;
    int Ns = 4;
    #pragma unroll
    for (int s = 1; s < 5; s++) {
        const int ls = 2 * s;
        const int j = t;
        float2 v0 = sb[SW(j)];
        float2 v1 = sb[SW(j + 512)];
        float2 v2 = sb[SW(j + 1024)];
        float2 v3 = sb[SW(j + 1536)];
        int jm = j & (Ns - 1);
        float c1, s1;
        if (s <= 2) {
            float2 e1 = expk[jm << (12 - 2 * s)];
            c1 = e1.x; s1 = e1.y;
        } else {
            __sincosf((0.5f * PI_F) * (float)jm / (float)Ns, &s1, &c1);
        }
        float c2 = c1 * c1 - s1 * s1, s2 = 2.0f * c1 * s1;
        float c3 = c1 * c2 - s1 * s2, s3 = c1 * s2 + s1 * c2;
        v1 = cmulf(v1, c1, s1);
        v2 = cmulf(v2, c2, s2);
        v3 = cmulf(v3, c3, s3);
        int idxD = ((j >> ls) << (ls + 2)) | jm;
        BFLY4(v0, v1, v2, v3,
              db[SW(idxD)], db[SW(idxD + Ns)],
              db[SW(idxD + 2 * Ns)], db[SW(idxD + 3 * Ns)]);
        __syncthreads();
        float2* tmp = sb; sb = db; db = tmp;
        Ns <<= 2;
    }

    {
        int j  = t;
        int jB = 1023 - t;
        float2 a0 = sb[SW(j)];
        float2 a1 = sb[SW(j + 1024)];
        float2 b0 = sb[SW(jB)];
        float2 b1 = sb[SW(jB + 1024)];
        float sA, cA, sB, cB;
        __sincosf(PI_F * (float)j  * (1.0f / 1024.0f), &sA, &cA);
        __sincosf(PI_F * (float)jB * (1.0f / 1024.0f), &sB, &cB);
        float2 wa1 = cmulf(a1, cA, sA);
        float2 wb1 = cmulf(b1, cB, sB);
        float2 zA0 = make_float2(a0.x + wa1.x, a0.y + wa1.y);
        float2 zA1 = make_float2(a0.x - wa1.x, a0.y - wa1.y);
        float2 zB0 = make_float2(b0.x + wb1.x, b0.y + wb1.y);
        float2 zB1 = make_float2(b0.x - wb1.x, b0.y - wb1.y);
        float4 oA, oB;
        if (IDXST) {
            oA = make_float4(zA0.x, -zB1.y, zA0.y, -zB1.x);
            oB = make_float4(zB0.x, -zA1.y, zB0.y, -zA1.x);
        } else {
            oA = make_float4(zA0.x,  zB1.y, zA0.y,  zB1.x);
            oB = make_float4(zB0.x,  zA1.y, zB0.y,  zA1.x);
        }
        float4* d4 = (float4*)dst;
        d4[j]  = oA;
        d4[jB] = oB;
    }
}

// ---------------------------------------------------------------------------
// Four-step column IDCT along M (length 4096), no transpose.
// 2048-pt IFFT = DFT-64 (over m1, stride-32 rows) x twiddle x DFT-32 (over m2).
// All DFT work in registers; every global access is lane-contiguous (256 B+).
// ---------------------------------------------------------------------------

// P1: thread (col, m2): build Z[k], k = 32*m1 + m2, from G (Makhoul IDCT
// prologue, identical math to row kernel's IDXST=false branch); register
// DFT-64 over m1 (+i, Stockham, natural-order out); four-step twiddle
// e^{+2 pi i m1' m2 / 2048}; write W row (32*m1' + m2).
__global__ __launch_bounds__(256)
void col_pass1(const float* __restrict__ g, float2* __restrict__ w,
               const float2* __restrict__ expk)
{
    const int col = blockIdx.x * 64 + threadIdx.x;       // lanes = cols
    const int m2  = blockIdx.y * 4 + threadIdx.y;        // wave-uniform, 0..31
    const float* G = g + (size_t)blockIdx.z * 4096 * 4096;
    float2*      W = w + (size_t)blockIdx.z * 2048 * 4096;

    float2 za[64], zb[64];

    // ---- Z-build (Makhoul IDCT prologue along M) ----
    #pragma unroll
    for (int m1 = 0; m1 < 64; m1++) {
        int k = 32 * m1 + m2;                            // 0..2047
        float Xa  = G[(size_t)k * 4096 + col];
        float Xra = (k == 0) ? 0.0f : G[(size_t)(4096 - k) * 4096 + col];
        float Xb  = G[(size_t)(2048 + k) * 4096 + col];
        float Xrb = G[(size_t)(2048 - k) * 4096 + col];
        float2 ea = expk[k];                             // wave-uniform
        float2 eb = expk[k + 2048];
        float Var = 0.5f * (Xa * ea.x + Xra * ea.y);
        float Vai = 0.5f * (Xa * ea.y - Xra * ea.x);
        float Vbr = 0.5f * (Xb * eb.x + Xrb * eb.y);
        float Vbi = 0.5f * (Xb * eb.y - Xrb * eb.x);
        float Ar = Var + Vbr, Ai = Vai + Vbi;
        float Dr = Var - Vbr, Di = Vai - Vbi;
        float cw, sw;
        __sincosf(PI_F * (float)k * (1.0f / 2048.0f), &sw, &cw);
        float Br = Dr * cw - Di * sw;
        float Bi = Dr * sw + Di * cw;
        za[m1] = make_float2(Ar - Bi, Ai + Br);
    }

    // ---- DFT-64 over m1, +i, Stockham radix-4 x3, natural-order output ----
    // stage 0: Ns=1 (twiddle-free)
    #pragma unroll
    for (int j = 0; j < 16; j++) {
        float2 v0 = za[j], v1 = za[j + 16], v2 = za[j + 32], v3 = za[j + 48];
        BFLY4(v0, v1, v2, v3, zb[4 * j], zb[4 * j + 1], zb[4 * j + 2], zb[4 * j + 3]);
    }
    // stage 1: Ns=4, twiddle W16^jm
    #pragma unroll
    for (int j = 0; j < 16; j++) {
        float2 v0 = zb[j], v1 = zb[j + 16], v2 = zb[j + 32], v3 = zb[j + 48];
        int jm = j & 3;
        float s1, c1;
        __sincosf((2.0f * PI_F / 16.0f) * (float)jm, &s1, &c1);
        float c2 = c1 * c1 - s1 * s1, s2 = 2.0f * c1 * s1;
        float c3 = c1 * c2 - s1 * s2, s3 = c1 * s2 + s1 * c2;
        v1 = cmulf(v1, c1, s1);
        v2 = cmulf(v2, c2, s2);
        v3 = cmulf(v3, c3, s3);
        int d = ((j >> 2) << 4) | jm;
        BFLY4(v0, v1, v2, v3, za[d], za[d + 4], za[d + 8], za[d + 12]);
    }
    // stage 2: Ns=16, twiddle W64^j
    #pragma unroll
    for (int j = 0; j < 16; j++) {
        float2 v0 = za[j], v1 = za[j + 16], v2 = za[j + 32], v3 = za[j + 48];
        float s1, c1;
        __sincosf((2.0f * PI_F / 64.0f) * (float)j, &s1, &c1);
        float c2 = c1 * c1 - s1 * s1, s2 = 2.0f * c1 * s1;
        float c3 = c1 * c2 - s1 * s2, s3 = c1 * s2 + s1 * c2;
        v1 = cmulf(v1, c1, s1);
        v2 = cmulf(v2, c2, s2);
        v3 = cmulf(v3, c3, s3);
        BFLY4(v0, v1, v2, v3, zb[j], zb[j + 16], zb[j + 32], zb[j + 48]);
    }

    // ---- four-step twiddle + strided store (lane-contiguous 512 B) ----
    const float theta = (2.0f * PI_F / 2048.0f) * (float)m2;  // wave-uniform
    #pragma unroll
    for (int m1p = 0; m1p < 64; m1p++) {
        float st, ct;
        __sincosf(theta * (float)m1p, &st, &ct);
        W[(size_t)(32 * m1p + m2) * 4096 + col] = cmulf(zb[m1p], ct, st);
    }
}

// P2: thread (col, p): read W rows {32p+m2, 32(63-p)+m2}; dual register
// DFT-32 over m2 (+i); fused Makhoul de-interleave along M; scalar
// (lane-contiguous) stores of the real output.
__global__ __launch_bounds__(256)
void col_pass2(const float2* __restrict__ w, float* __restrict__ y)
{
    const int col = blockIdx.x * 64 + threadIdx.x;
    const int p   = blockIdx.y * 4 + threadIdx.y;        // 0..31
    const int pb  = 63 - p;
    const float2* W = w + (size_t)blockIdx.z * 2048 * 4096;
    float*        Y = y + (size_t)blockIdx.z * 4096 * 4096;

    float2 va[32], wa[32], vb[32], wb[32];
    #pragma unroll
    for (int m2 = 0; m2 < 32; m2++) {
        va[m2] = W[(size_t)(32 * p  + m2) * 4096 + col];
        vb[m2] = W[(size_t)(32 * pb + m2) * 4096 + col];
    }

    // ---- dual DFT-32, +i, Stockham: radix-4 (Ns=1), radix-4 (Ns=4), radix-2 ----
    // stage 0: Ns=1
    #pragma unroll
    for (int j = 0; j < 8; j++) {
        float2 v0 = va[j], v1 = va[j + 8], v2 = va[j + 16], v3 = va[j + 24];
        BFLY4(v0, v1, v2, v3, wa[4 * j], wa[4 * j + 1], wa[4 * j + 2], wa[4 * j + 3]);
        float2 u0 = vb[j], u1 = vb[j + 8], u2 = vb[j + 16], u3 = vb[j + 24];
        BFLY4(u0, u1, u2, u3, wb[4 * j], wb[4 * j + 1], wb[4 * j + 2], wb[4 * j + 3]);
    }
    // stage 1: Ns=4, twiddle W16^jm
    #pragma unroll
    for (int j = 0; j < 8; j++) {
        int jm = j & 3;
        float s1, c1;
        __sincosf((2.0f * PI_F / 16.0f) * (float)jm, &s1, &c1);
        float c2 = c1 * c1 - s1 * s1, s2 = 2.0f * c1 * s1;
        float c3 = c1 * c2 - s1 * s2, s3 = c1 * s2 + s1 * c2;
        int d = ((j >> 2) << 4) | jm;
        float2 v0 = wa[j], v1 = wa[j + 8], v2 = wa[j + 16], v3 = wa[j + 24];
        v1 = cmulf(v1, c1, s1); v2 = cmulf(v2, c2, s2); v3 = cmulf(v3, c3, s3);
        BFLY4(v0, v1, v2, v3, va[d], va[d + 4], va[d + 8], va[d + 12]);
        float2 u0 = wb[j], u1 = wb[j + 8], u2 = wb[j + 16], u3 = wb[j + 24];
        u1 = cmulf(u1, c1, s1); u2 = cmulf(u2, c2, s2); u3 = cmulf(u3, c3, s3);
        BFLY4(u0, u1, u2, u3, vb[d], vb[d + 4], vb[d + 8], vb[d + 12]);
    }
    // stage 2: radix-2, Ns=16, twiddle W32^j
    #pragma unroll
    for (int j = 0; j < 16; j++) {
        float s1, c1;
        __sincosf((2.0f * PI_F / 32.0f) * (float)j, &s1, &c1);
        float2 tA = cmulf(va[j + 16], c1, s1);
        wa[j]      = make_float2(va[j].x + tA.x, va[j].y + tA.y);
        wa[j + 16] = make_float2(va[j].x - tA.x, va[j].y - tA.y);
        float2 tB = cmulf(vb[j + 16], c1, s1);
        wb[j]      = make_float2(vb[j].x + tB.x, vb[j].y + tB.y);
        wb[j + 16] = make_float2(vb[j].x - tB.x, vb[j].y - tB.y);
    }
    // wa[m2'] = z[p + 64 m2'], wb[m2'] = z[(63-p) + 64 m2']

    // ---- de-interleave: y4p'=Re z_p'; y4p'+1=Im z_{2047-p'};
    //      y4p'+2=Im z_p'; y4p'+3=Re z_{2047-p'} ----
    #pragma unroll
    for (int q = 0; q < 16; q++) {
        int p1 = p  + 64 * q;                 // < 1024
        int p2 = pb + 64 * q;                 // < 1024
        float2 z1  = wa[q];                   // z[p1]
        float2 z1m = wb[31 - q];              // z[2047 - p1]
        float2 z2  = wb[q];                   // z[p2]
        float2 z2m = wa[31 - q];              // z[2047 - p2]
        Y[(size_t)(4 * p1 + 0) * 4096 + col] = z1.x;
        Y[(size_t)(4 * p1 + 1) * 4096 + col] = z1m.y;
        Y[(size_t)(4 * p1 + 2) * 4096 + col] = z1.y;
        Y[(size_t)(4 * p1 + 3) * 4096 + col] = z1m.x;
        Y[(size_t)(4 * p2 + 0) * 4096 + col] = z2.x;
        Y[(size_t)(4 * p2 + 1) * 4096 + col] = z2m.y;
        Y[(size_t)(4 * p2 + 2) * 4096 + col] = z2.y;
        Y[(size_t)(4 * p2 + 3) * 4096 + col] = z2m.x;
    }
}

// ---------------------------------------------------------------------------
// Fallback transpose (verified) — used only if ws is too small.
// ---------------------------------------------------------------------------
__global__ __launch_bounds__(256)
void transpose_inplace(float* d, int n)
{
    __shared__ float ta[64][65];
    __shared__ float tb[64][65];
    int ti = blockIdx.x, tj = blockIdx.y, b = blockIdx.z;
    if (tj < ti) return;
    float* base = d + (size_t)b * n * n;
    const int t  = threadIdx.x;
    const int c4 = t & 15;
    const int r0 = t >> 4;
    size_t offA = (size_t)(ti * 64) * n + tj * 64;
    size_t offB = (size_t)(tj * 64) * n + ti * 64;

    #pragma unroll
    for (int q = 0; q < 4; q++) {
        int r = r0 + 16 * q;
        float4 va = ((const float4*)(base + offA + (size_t)r * n))[c4];
        ta[r][4 * c4 + 0] = va.x; ta[r][4 * c4 + 1] = va.y;
        ta[r][4 * c4 + 2] = va.z; ta[r][4 * c4 + 3] = va.w;
    }
    if (ti != tj) {
        #pragma unroll
        for (int q = 0; q < 4; q++) {
            int r = r0 + 16 * q;
            float4 vb = ((const float4*)(base + offB + (size_t)r * n))[c4];
            tb[r][4 * c4 + 0] = vb.x; tb[r][4 * c4 + 1] = vb.y;
            tb[r][4 * c4 + 2] = vb.z; tb[r][4 * c4 + 3] = vb.w;
        }
    }
    __syncthreads();

    if (ti != tj) {
        #pragma unroll
        for (int q = 0; q < 4; q++) {
            int r = r0 + 16 * q;
            float4 o;
            o.x = tb[4 * c4 + 0][r]; o.y = tb[4 * c4 + 1][r];
            o.z = tb[4 * c4 + 2][r]; o.w = tb[4 * c4 + 3][r];
            ((float4*)(base + offA + (size_t)r * n))[c4] = o;
            float4 pp;
            pp.x = ta[4 * c4 + 0][r]; pp.y = ta[4 * c4 + 1][r];
            pp.z = ta[4 * c4 + 2][r]; pp.w = ta[4 * c4 + 3][r];
            ((float4*)(base + offB + (size_t)r * n))[c4] = pp;
        }
    } else {
        #pragma unroll
        for (int q = 0; q < 4; q++) {
            int r = r0 + 16 * q;
            float4 pp;
            pp.x = ta[4 * c4 + 0][r]; pp.y = ta[4 * c4 + 1][r];
            pp.z = ta[4 * c4 + 2][r]; pp.w = ta[4 * c4 + 3][r];
            ((float4*)(base + offA + (size_t)r * n))[c4] = pp;
        }
    }
}

extern "C" void kernel_launch(void* const* d_in, const int* in_sizes, int n_in,
                              void* d_out, int out_size, void* d_ws, size_t ws_size,
                              hipStream_t stream)
{
    const float*  x     = (const float*)d_in[0];
    const float2* expkM = (const float2*)d_in[1];   // (4096, 2) fp32
    const float2* expkN = (const float2*)d_in[2];   // (4096, 2) fp32
    float* out = (float*)d_out;

    const int B = in_sizes[0] / (4096 * 4096);      // = 2
    const int rows = B * 4096;

    // IDXST along N (contiguous rows of x) -> out.
    row_fft_kernel<true><<<rows, 512, 0, stream>>>(x, out, expkN);

    const size_t need = (size_t)B * 2048 * 4096 * sizeof(float2);  // 134 MB
    if (d_ws && ws_size >= need) {
        // Four-step IDCT along M, transpose-free.
        float2* W = (float2*)d_ws;
        col_pass1<<<dim3(64, 8, B), dim3(64, 4), 0, stream>>>(out, W, expkM);
        col_pass2<<<dim3(64, 8, B), dim3(64, 4), 0, stream>>>(W, out);
    } else {
        // Fallback: verified transpose + row IDCT + transpose.
        transpose_inplace<<<dim3(64, 64, B), dim3(256), 0, stream>>>(out, 4096);
        row_fft_kernel<false><<<rows, 512, 0, stream>>>(out, out, expkM);
        transpose_inplace<<<dim3(64, 64, B), dim3(256), 0, stream>>>(out, 4096);
    }
}